// Round 1
// baseline (377.241 us; speedup 1.0000x reference)
//
#include <hip/hip_runtime.h>

#define H_IMG 1024
#define W_IMG 1024
#define N_IMG 16
#define C_IMG 3

__global__ __launch_bounds__(256) void homography_warp_kernel(
    const float* __restrict__ img,   // [N, 3, H, W]
    const float* __restrict__ homo,  // [N, 3, 3]
    float* __restrict__ out)         // [N, 3, H, W]
{
    const int n   = blockIdx.y;
    const int pix = blockIdx.x * 256 + threadIdx.x;   // pixel index within image
    const int h   = pix >> 10;                         // W_IMG == 1024
    const int w   = pix & (W_IMG - 1);

    // Block-uniform homography coefficients (blockIdx.y-indexed -> scalar loads)
    const float* Hm = homo + n * 9;
    const float h00 = Hm[0], h01 = Hm[1], h02 = Hm[2];
    const float h10 = Hm[3], h11 = Hm[4], h12 = Hm[5];
    const float h20 = Hm[6], h21 = Hm[7], h22 = Hm[8];

    // Normalized meshgrid coords in [-1, 1] (matches jnp.linspace endpoints)
    const float gx = fmaf((float)w, 2.0f / (W_IMG - 1), -1.0f);
    const float gy = fmaf((float)h, 2.0f / (H_IMG - 1), -1.0f);

    // Homogeneous transform
    const float tx = fmaf(h00, gx, fmaf(h01, gy, h02));
    const float ty = fmaf(h10, gx, fmaf(h11, gy, h12));
    const float tz = fmaf(h20, gx, fmaf(h21, gy, h22));
    const float inv = 1.0f / tz;   // accurate fp32 division (no fast-math)
    const float u = tx * inv;
    const float v = ty * inv;

    // Map to pixel coords (align_corners=True)
    const float xp = (u + 1.0f) * 0.5f * (float)(W_IMG - 1);
    const float yp = (v + 1.0f) * 0.5f * (float)(H_IMG - 1);

    const float x0f = floorf(xp);
    const float y0f = floorf(yp);
    const float fx = xp - x0f;
    const float fy = yp - y0f;

    const int ix0 = (int)x0f;
    const int iy0 = (int)y0f;
    const int ix1 = ix0 + 1;
    const int iy1 = iy0 + 1;

    // zeros-padding validity per corner, folded into the bilinear weights
    const float vx0 = (ix0 >= 0 && ix0 < W_IMG) ? 1.0f : 0.0f;
    const float vx1 = (ix1 >= 0 && ix1 < W_IMG) ? 1.0f : 0.0f;
    const float vy0 = (iy0 >= 0 && iy0 < H_IMG) ? 1.0f : 0.0f;
    const float vy1 = (iy1 >= 0 && iy1 < H_IMG) ? 1.0f : 0.0f;

    const float w00 = (1.0f - fx) * (1.0f - fy) * vx0 * vy0;
    const float w01 = fx * (1.0f - fy) * vx1 * vy0;
    const float w10 = (1.0f - fx) * fy * vx0 * vy1;
    const float w11 = fx * fy * vx1 * vy1;

    // Clipped gather indices (OOB lanes have weight 0 anyway)
    const int cx0 = min(max(ix0, 0), W_IMG - 1);
    const int cx1 = min(max(ix1, 0), W_IMG - 1);
    const int cy0 = min(max(iy0, 0), H_IMG - 1);
    const int cy1 = min(max(iy1, 0), H_IMG - 1);

    const int o00 = cy0 * W_IMG + cx0;
    const int o01 = cy0 * W_IMG + cx1;
    const int o10 = cy1 * W_IMG + cx0;
    const int o11 = cy1 * W_IMG + cx1;

    const size_t plane = (size_t)H_IMG * W_IMG;
    const size_t base  = (size_t)n * C_IMG * plane;

#pragma unroll
    for (int c = 0; c < C_IMG; ++c) {
        const float* p = img + base + (size_t)c * plane;
        const float r = w00 * p[o00] + w01 * p[o01] + w10 * p[o10] + w11 * p[o11];
        out[base + (size_t)c * plane + (size_t)pix] = r;
    }
}

extern "C" void kernel_launch(void* const* d_in, const int* in_sizes, int n_in,
                              void* d_out, int out_size, void* d_ws, size_t ws_size,
                              hipStream_t stream) {
    const float* img  = (const float*)d_in[0];   // patch_src  [16,3,1024,1024]
    const float* homo = (const float*)d_in[1];   // dst_homo_src [16,3,3]
    float* out = (float*)d_out;                  // [16,3,1024,1024] fp32

    dim3 block(256);
    dim3 grid((H_IMG * W_IMG) / 256, N_IMG);
    homography_warp_kernel<<<grid, block, 0, stream>>>(img, homo, out);
}